// Round 5
// baseline (140.555 us; speedup 1.0000x reference)
//
#include <hip/hip_runtime.h>

#define BB 16
#define CC 512
#define NN 192
#define CS 128
#define CR 64
#define EPSF 1e-5f
#define PART (BB*CC*NN)                    // 1572864

typedef __attribute__((ext_vector_type(8))) short short8;
typedef __attribute__((ext_vector_type(4))) float f32x4;
typedef __attribute__((ext_vector_type(4))) unsigned int uint4v;

// ---------------- workspace layout (float units) ----------------
#define OFF_LIN2  0                        // 786432; dead after k3 -> attpx aliases
#define OFF_ATTPX 0                        // 1572864
#define OFF_P2    1572864                  // 196608  p2raw[b][i][o] (unscaled)
#define OFF_QT    1769472                  // 196608  qTraw[b][j][o] (unscaled)
#define OFF_ATTP3 1966080                  // 3*1572864, ends 6684672
#define OFF_WBF   6684672                  // short[512*12800] = 3276800 floats
#define OFF_XT    9961472                  // short[16*192*512] = 786432 floats
#define OFF_ROWS  10747904                 // 16384
#define OFF_SPART 10764288                 // 24576 (sum 12288 + sq 12288)
#define OFF_SCL   10788864                 // 640

__device__ __forceinline__ unsigned pkbf(float a, float b){
  unsigned r; asm("v_cvt_pk_bf16_f32 %0, %1, %2" : "=v"(r) : "v"(a), "v"(b)); return r;
}

__device__ __forceinline__ void gload_lds16(const void* g, void* l){
  __builtin_amdgcn_global_load_lds(
      (const __attribute__((address_space(1))) unsigned int*)g,
      (__attribute__((address_space(3))) unsigned int*)l, 16, 0, 0);
}

// KCONVXT: att_w -> bf16 wbf (blocks 0..3199); inputs -> xT bf16 [b][n][c] (3200..3583)
__global__ __launch_bounds__(256) void kconvxt(
    const float* __restrict__ aw, const float* __restrict__ x,
    short* __restrict__ wbf, short* __restrict__ xT)
{
  __shared__ float Ts[64][65];
  if (blockIdx.x < 3200) {
    int t = blockIdx.x*256 + threadIdx.x;
    int o2 = t / 1600;
    int kk = (t - o2*1600) * 8;
    const float* src = &aw[o2*12800 + kk];
    float4 v0 = *reinterpret_cast<const float4*>(src);
    float4 v1 = *reinterpret_cast<const float4*>(src+4);
    uint4v w;
    w.x = pkbf(v0.x, v0.y); w.y = pkbf(v0.z, v0.w);
    w.z = pkbf(v1.x, v1.y); w.w = pkbf(v1.z, v1.w);
    *reinterpret_cast<uint4v*>(&wbf[o2*12800 + kk]) = w;
  } else {
    int bid = blockIdx.x - 3200;    // 384 = b16 * ct8 * nt3
    int nt = bid % 3; int ct = (bid/3) & 7; int b = bid / 24;
    int c0 = ct*64, n0 = nt*64;
    int tid = threadIdx.x;
    int col = tid & 63, r0 = tid >> 6;
    #pragma unroll
    for (int it = 0; it < 16; ++it){
      int r = r0 + it*4;
      Ts[r][col] = x[(b*CC + c0 + r)*NN + n0 + col];
    }
    __syncthreads();
    #pragma unroll
    for (int it = 0; it < 2; ++it){
      int cp = it*256 + tid;
      int nr = cp >> 3, cc8 = (cp & 7)*8;
      uint4v wv;
      wv.x = pkbf(Ts[cc8+0][nr], Ts[cc8+1][nr]);
      wv.y = pkbf(Ts[cc8+2][nr], Ts[cc8+3][nr]);
      wv.z = pkbf(Ts[cc8+4][nr], Ts[cc8+5][nr]);
      wv.w = pkbf(Ts[cc8+6][nr], Ts[cc8+7][nr]);
      *reinterpret_cast<uint4v*>(&xT[((b*NN) + n0 + nr)*CC + c0 + cc8]) = wv;
    }
  }
}

// K1: lin2[b][path*128+cs][n] = sum_c W[cs,c]*x[b,c,n] + per-block partial BN stats
__global__ __launch_bounds__(256) void k1_lin(
    const float* __restrict__ x, const float* __restrict__ wth,
    const float* __restrict__ wph, float* __restrict__ lin2,
    float* __restrict__ spart)
{
  int bid = blockIdx.x;            // 192 = path2 * b16 * ch2 * nt3
  int nt = bid % 3; int ch = (bid/3) & 1; int b = (bid/6) & 15; int path = bid/96;
  int cs0 = ch*64, n0 = nt*64;
  const float* w = path ? wph : wth;
  int tid = threadIdx.x;
  int ty = tid >> 4, tx = tid & 15;
  __shared__ float Xs[32][64];
  __shared__ float Ws[32][68];
  float acc[4][4];
  #pragma unroll
  for (int i=0;i<4;++i)
    #pragma unroll
    for (int j=0;j<4;++j) acc[i][j]=0.f;
  for (int c0 = 0; c0 < CC; c0 += 32){
    __syncthreads();
    {
      int nn = tid & 63, cb = tid >> 6;
      #pragma unroll
      for (int it = 0; it < 8; ++it)
        Xs[cb + it*4][nn] = x[(b*CC + c0 + cb + it*4)*NN + n0 + nn];
    }
    {
      int cc = tid & 31, sb = tid >> 5;
      #pragma unroll
      for (int it = 0; it < 8; ++it)
        Ws[cc][sb + it*8] = w[(cs0 + sb + it*8)*CC + c0 + cc];
    }
    __syncthreads();
    #pragma unroll 8
    for (int cc = 0; cc < 32; ++cc){
      float w4[4], x4[4];
      *reinterpret_cast<float4*>(w4) = *reinterpret_cast<const float4*>(&Ws[cc][ty*4]);
      *reinterpret_cast<float4*>(x4) = *reinterpret_cast<const float4*>(&Xs[cc][tx*4]);
      #pragma unroll
      for (int i=0;i<4;++i)
        #pragma unroll
        for (int j=0;j<4;++j) acc[i][j] += w4[i]*x4[j];
    }
  }
  #pragma unroll
  for (int r = 0; r < 4; ++r){
    int cs = cs0 + ty*4 + r;
    float4 v = make_float4(acc[r][0],acc[r][1],acc[r][2],acc[r][3]);
    *reinterpret_cast<float4*>(&lin2[(b*256 + path*128 + cs)*NN + n0 + tx*4]) = v;
  }
  // partial BN stats over this block's 64-n slice
  #pragma unroll
  for (int r = 0; r < 4; ++r){
    float s = acc[r][0]+acc[r][1]+acc[r][2]+acc[r][3];
    float q = acc[r][0]*acc[r][0]+acc[r][1]*acc[r][1]
            + acc[r][2]*acc[r][2]+acc[r][3]*acc[r][3];
    #pragma unroll
    for (int off=8; off; off>>=1){ s += __shfl_down(s,off,16); q += __shfl_down(q,off,16); }
    if (tx==0){
      int cs2 = path*128 + cs0 + ty*4 + r;
      spart[cs2*48 + b*3 + nt] = s;
      spart[12288 + cs2*48 + b*3 + nt] = q;
    }
  }
}

// K2FIN: reduce 48 partials per channel -> scl[cs2], scl[256+cs2]
__global__ void k2_fin(const float* __restrict__ spart,
    const float* __restrict__ tg, const float* __restrict__ tbe,
    const float* __restrict__ pg, const float* __restrict__ pbe,
    float* __restrict__ scl)
{
  int c2 = threadIdx.x;  // 256
  float s=0.f, q=0.f;
  #pragma unroll 8
  for (int i=0;i<48;++i){ s += spart[c2*48+i]; q += spart[12288+c2*48+i]; }
  float mean = s * (1.f/3072.f);
  float var = q * (1.f/3072.f) - mean*mean;
  int path = c2 >> 7, c = c2 & 127;
  float g  = path ? pg[c]  : tg[c];
  float be = path ? pbe[c] : tbe[c];
  float a = g * rsqrtf(var + EPSF);
  scl[c2] = a; scl[256+c2] = be - mean*a;
}

// K3: raw A/B GEMM with fused BN+relu staging; writes TRANSPOSED raw outputs
// p2raw[b][i][o], qTraw[b][j][o]; plus per-row partial sums for rel-BN.
__global__ __launch_bounds__(256) void k3_gemm(
    const float* __restrict__ lin2, const float* __restrict__ scl,
    const float* __restrict__ rw,
    float* __restrict__ p2raw, float* __restrict__ qTraw,
    float* __restrict__ rows4)
{
  int bid = blockIdx.x;            // 128 = path2 * b16 * ih4
  int ih = bid & 3; int b = (bid>>2) & 15; int path = bid >> 6;
  int i0 = ih*48;
  __shared__ float Ls[128][48];
  __shared__ float Ws[64][132];
  int tid = threadIdx.x;
  #pragma unroll
  for (int it = 0; it < 6; ++it){
    int cp = it*256 + tid;
    int row = cp / 12, c4 = cp - row*12;
    float a = scl[path*128 + row], d = scl[256 + path*128 + row];
    float4 v = *reinterpret_cast<const float4*>(&lin2[(b*256 + path*128 + row)*NN + i0 + c4*4]);
    float4 r;
    r.x = fmaxf(a*v.x + d, 0.f); r.y = fmaxf(a*v.y + d, 0.f);
    r.z = fmaxf(a*v.z + d, 0.f); r.w = fmaxf(a*v.w + d, 0.f);
    *reinterpret_cast<float4*>(&Ls[row][c4*4]) = r;
  }
  #pragma unroll
  for (int it = 0; it < 8; ++it){
    int cp = it*256 + tid;
    int o = cp >> 5, c4 = cp & 31;
    *reinterpret_cast<float4*>(&Ws[o][c4*4]) =
      *reinterpret_cast<const float4*>(&rw[o*CS + c4*4]);
  }
  __syncthreads();
  int oy = tid >> 4, ix = tid & 15;
  float acc[4][3];
  #pragma unroll
  for (int r=0;r<4;++r)
    #pragma unroll
    for (int e=0;e<3;++e) acc[r][e]=0.f;
  #pragma unroll 4
  for (int c = 0; c < 128; ++c){
    float w4[4], l3[3];
    #pragma unroll
    for (int r=0;r<4;++r) w4[r] = Ws[oy*4+r][c];
    #pragma unroll
    for (int e=0;e<3;++e) l3[e] = Ls[c][ix*3+e];
    #pragma unroll
    for (int r=0;r<4;++r)
      #pragma unroll
      for (int e=0;e<3;++e) acc[r][e] += w4[r]*l3[e];
  }
  float* dst = path ? qTraw : p2raw;
  #pragma unroll
  for (int r=0;r<4;++r)
    #pragma unroll
    for (int e=0;e<3;++e)
      dst[(b*NN + i0 + ix*3 + e)*64 + oy*4 + r] = acc[r][e];
  // partial row sums over this block's 48-column slice
  #pragma unroll
  for (int r=0;r<4;++r){
    float s = acc[r][0]+acc[r][1]+acc[r][2];
    float q = acc[r][0]*acc[r][0]+acc[r][1]*acc[r][1]+acc[r][2]*acc[r][2];
    #pragma unroll
    for (int off=8; off; off>>=1){ s += __shfl_down(s,off,16); q += __shfl_down(q,off,16); }
    if (ix==0){
      int o = oy*4+r;
      int ri = (path*1024 + b*64 + o)*4 + ih;
      rows4[ri] = s; rows4[8192 + ri] = q;
    }
  }
}

// K4a: rel-BN closed form from 4-way partial row sums -> scl[512+o], scl[576+o]
__global__ void k4_relstats(const float* __restrict__ rows4,
    const float* __restrict__ rg, const float* __restrict__ rbe,
    float* __restrict__ scl)
{
  int o = threadIdx.x;  // 64
  float sa=0,saq=0,sb=0,sbq=0,cross=0;
  for (int b=0;b<BB;++b){
    float ra=0, rb=0;
    #pragma unroll
    for (int ih=0; ih<4; ++ih){
      int ia = (b*64+o)*4 + ih, ib = (1024 + b*64+o)*4 + ih;
      ra += rows4[ia]; rb += rows4[ib];
      saq += rows4[8192 + ia]; sbq += rows4[8192 + ib];
    }
    sa += ra; sb += rb; cross += ra*rb;
  }
  float mean = (sa - sb) * (1.f/3072.f);
  float e2 = (saq + sbq) * (1.f/3072.f) - cross * (2.f/589824.f);
  float var = e2 - mean*mean;
  float s = rg[o] * rsqrtf(var + EPSF);
  scl[512+o] = s;
  scl[576+o] = rbe[o] - s*mean;
}

// K5: att GEMM (x + rel parts), bf16 MFMA. B-operand fragments built fully in
// registers (no Bs LDS round-trip): lane-local pa[3][16] + q broadcast from LDS.
__global__ __launch_bounds__(256, 2) void k5_mfma(
    const short* __restrict__ wbf, const short* __restrict__ xT,
    const float* __restrict__ p2raw, const float* __restrict__ qTraw,
    const float* __restrict__ scl,
    float* __restrict__ attpx, float* __restrict__ attp3)
{
  int bid = blockIdx.x;            // 512 = ks4 * b16 * mt4 * nt2
  int nt = bid & 1, mt = (bid >> 1) & 3, b = (bid >> 3) & 15, ks = bid >> 7;
  int o20 = mt*128, n0 = nt*96;
  int j0 = ks*48;

  int tid = threadIdx.x;
  int w = tid >> 6, lane = tid & 63;
  int wr = w >> 1, wc = w & 1;
  int l15 = lane & 15, l4 = lane >> 4;
  int ob = l4*8;

  __shared__ __align__(16) short As[128*64];   // W tile, XOR-swizzled
  __shared__ __align__(16) float qlds[2][64];  // scaled q, double-slot

  float sq_ = scl[512 + (tid & 63)];

  // lane-local scaled p: pa[ni][s*8+t] = s_o*p2raw + sh_o at o = s*32+ob+t
  float pa[3][16];
  {
    float sc[16], sh[16];
    *reinterpret_cast<float4*>(&sc[0])  = *reinterpret_cast<const float4*>(&scl[512+ob]);
    *reinterpret_cast<float4*>(&sc[4])  = *reinterpret_cast<const float4*>(&scl[512+ob+4]);
    *reinterpret_cast<float4*>(&sc[8])  = *reinterpret_cast<const float4*>(&scl[512+32+ob]);
    *reinterpret_cast<float4*>(&sc[12]) = *reinterpret_cast<const float4*>(&scl[512+32+ob+4]);
    *reinterpret_cast<float4*>(&sh[0])  = *reinterpret_cast<const float4*>(&scl[576+ob]);
    *reinterpret_cast<float4*>(&sh[4])  = *reinterpret_cast<const float4*>(&scl[576+ob+4]);
    *reinterpret_cast<float4*>(&sh[8])  = *reinterpret_cast<const float4*>(&scl[576+32+ob]);
    *reinterpret_cast<float4*>(&sh[12]) = *reinterpret_cast<const float4*>(&scl[576+32+ob+4]);
    #pragma unroll
    for (int ni=0; ni<3; ++ni){
      const float* pb = &p2raw[(size_t)((b*NN) + n0 + wc*48 + ni*16 + l15)*64];
      float r[16];
      *reinterpret_cast<float4*>(&r[0])  = *reinterpret_cast<const float4*>(&pb[ob]);
      *reinterpret_cast<float4*>(&r[4])  = *reinterpret_cast<const float4*>(&pb[ob+4]);
      *reinterpret_cast<float4*>(&r[8])  = *reinterpret_cast<const float4*>(&pb[32+ob]);
      *reinterpret_cast<float4*>(&r[12]) = *reinterpret_cast<const float4*>(&pb[32+ob+4]);
      #pragma unroll
      for (int k=0;k<16;++k) pa[ni][k] = sc[k]*r[k] + sh[k];
    }
  }

  auto stageA = [&](int colbase){
    #pragma unroll
    for (int it=0; it<4; ++it){
      int cp = w*256 + it*64 + lane;
      int row = cp >> 3, c = (cp & 7) ^ (row & 7);
      gload_lds16(&wbf[(o20 + row)*12800 + colbase + c*8],
                  &As[(w*256 + it*64)*8]);
    }
  };

  f32x4 acc[4][3];
  #pragma unroll
  for (int mi=0;mi<4;++mi)
    #pragma unroll
    for (int ni=0;ni<3;++ni) acc[mi][ni] = (f32x4){0.f,0.f,0.f,0.f};

  auto mfma_phase = [&](short8 bvv[3][2]){
    #pragma unroll
    for (int s=0; s<2; ++s){
      short8 av[4];
      int c = s*4 + l4;
      #pragma unroll
      for (int mi=0; mi<4; ++mi){
        int row = wr*64 + mi*16 + l15;
        av[mi] = *reinterpret_cast<const short8*>(&As[row*64 + ((c ^ (row&7))<<3)]);
      }
      #pragma unroll
      for (int mi=0; mi<4; ++mi)
        #pragma unroll
        for (int ni=0; ni<3; ++ni)
          acc[mi][ni] = __builtin_amdgcn_mfma_f32_16x16x32_bf16(av[mi], bvv[ni][s], acc[mi][ni], 0, 0, 0);
    }
  };

  // ---- x-part: 2 iters, B straight from global xT (bf16, no LDS) ----
  stageA(ks*128);
  if (tid < 64) qlds[0][tid] = sq_ * qTraw[(size_t)(b*NN + j0)*64 + tid];
  short8 bvx[3][2];
  #pragma unroll
  for (int ni=0; ni<3; ++ni)
    #pragma unroll
    for (int s=0; s<2; ++s)
      bvx[ni][s] = *reinterpret_cast<const short8*>(
        &xT[(size_t)((b*NN) + n0 + wc*48 + ni*16 + l15)*CC + ks*128 + s*32 + ob]);
  __syncthreads();
  mfma_phase(bvx);
  __syncthreads();
  stageA(ks*128 + 64);
  #pragma unroll
  for (int ni=0; ni<3; ++ni)
    #pragma unroll
    for (int s=0; s<2; ++s)
      bvx[ni][s] = *reinterpret_cast<const short8*>(
        &xT[(size_t)((b*NN) + n0 + wc*48 + ni*16 + l15)*CC + ks*128 + 64 + s*32 + ob]);
  __syncthreads();
  mfma_phase(bvx);

  // ---- rel part: 48 j-iters, B generated in registers ----
  for (int kt = 0; kt < 48; ++kt){
    __syncthreads();                              // As consumed by previous mfma
    stageA(512 + (j0 + kt)*64);
    if (tid < 64 && kt < 47)
      qlds[(kt+1)&1][tid] = sq_ * qTraw[(size_t)(b*NN + j0 + kt + 1)*64 + tid];
    const float* qq = qlds[kt&1];
    float ql[16];
    *reinterpret_cast<float4*>(&ql[0])  = *reinterpret_cast<const float4*>(&qq[ob]);
    *reinterpret_cast<float4*>(&ql[4])  = *reinterpret_cast<const float4*>(&qq[ob+4]);
    *reinterpret_cast<float4*>(&ql[8])  = *reinterpret_cast<const float4*>(&qq[32+ob]);
    *reinterpret_cast<float4*>(&ql[12]) = *reinterpret_cast<const float4*>(&qq[32+ob+4]);
    short8 bvv[3][2];
    #pragma unroll
    for (int ni=0; ni<3; ++ni){
      #pragma unroll
      for (int s=0; s<2; ++s){
        uint4v u;
        u.x = pkbf(fmaxf(pa[ni][s*8+0]-ql[s*8+0],0.f), fmaxf(pa[ni][s*8+1]-ql[s*8+1],0.f));
        u.y = pkbf(fmaxf(pa[ni][s*8+2]-ql[s*8+2],0.f), fmaxf(pa[ni][s*8+3]-ql[s*8+3],0.f));
        u.z = pkbf(fmaxf(pa[ni][s*8+4]-ql[s*8+4],0.f), fmaxf(pa[ni][s*8+5]-ql[s*8+5],0.f));
        u.w = pkbf(fmaxf(pa[ni][s*8+6]-ql[s*8+6],0.f), fmaxf(pa[ni][s*8+7]-ql[s*8+7],0.f));
        bvv[ni][s] = *reinterpret_cast<short8*>(&u);
      }
    }
    __syncthreads();                              // drain vmcnt (stageA) + lgkm
    mfma_phase(bvv);
  }

  float* dst = (ks == 0) ? attpx : (attp3 + (size_t)(ks-1)*PART);
  #pragma unroll
  for (int mi=0; mi<4; ++mi){
    #pragma unroll
    for (int r=0; r<4; ++r){
      int o2 = o20 + wr*64 + mi*16 + l4*4 + r;
      #pragma unroll
      for (int ni=0; ni<3; ++ni){
        int n = n0 + wc*48 + ni*16 + l15;
        dst[(b*CC + o2)*NN + n] = acc[mi][ni][r];
      }
    }
  }
}

// K67: per-channel: sum 4 partials (regs) -> BN stats -> sigmoid -> out[b,o2]
__global__ __launch_bounds__(256) void k67(
    const float* __restrict__ px, const float* __restrict__ p3,
    const float* __restrict__ x,
    const float* __restrict__ g, const float* __restrict__ be,
    float* __restrict__ out)
{
  int o2 = blockIdx.x;   // 512
  int tid = threadIdx.x;
  int b = tid >> 4, nl = tid & 15;
  int base = (b*CC + o2)*NN + nl;
  float v[12], xv[12];
  float s=0.f, q=0.f;
  #pragma unroll
  for (int it=0; it<12; ++it){
    int idx = base + it*16;
    float t = px[idx] + p3[idx] + p3[PART+idx] + p3[2*PART+idx];
    v[it] = t; s += t; q += t*t;
    xv[it] = x[idx];
  }
  __shared__ float rs[4], rq[4], ad[2];
  #pragma unroll
  for (int off=32; off; off>>=1){ s += __shfl_down(s,off); q += __shfl_down(q,off); }
  int w = tid >> 6;
  if ((tid & 63)==0){ rs[w]=s; rq[w]=q; }
  __syncthreads();
  if (tid==0){
    s = rs[0]+rs[1]+rs[2]+rs[3]; q = rq[0]+rq[1]+rq[2]+rq[3];
    float mean = s * (1.f/3072.f);
    float var = q * (1.f/3072.f) - mean*mean;
    float a = g[o2] * rsqrtf(var + EPSF);
    ad[0] = a; ad[1] = be[o2] - mean*a;
  }
  __syncthreads();
  float a = ad[0], d = ad[1];
  float sf=0.f, ss=0.f;
  #pragma unroll
  for (int it=0; it<12; ++it){
    float sig = 1.f/(1.f + expf(-(a*v[it] + d)));
    sf += sig * xv[it]; ss += sig;
  }
  #pragma unroll
  for (int off=8; off; off>>=1){ sf += __shfl_down(sf,off,16); ss += __shfl_down(ss,off,16); }
  if (nl==0) out[b*CC + o2] = sf/ss;
}

extern "C" void kernel_launch(void* const* d_in, const int* in_sizes, int n_in,
                              void* d_out, int out_size, void* d_ws, size_t ws_size,
                              hipStream_t stream)
{
  const float* inputs  = (const float*)d_in[0];
  const float* theta_w = (const float*)d_in[2];
  const float* theta_g = (const float*)d_in[4];
  const float* theta_be= (const float*)d_in[5];
  const float* phi_w   = (const float*)d_in[6];
  const float* phi_g   = (const float*)d_in[8];
  const float* phi_be  = (const float*)d_in[9];
  const float* re_w    = (const float*)d_in[10];
  const float* re_g    = (const float*)d_in[12];
  const float* re_be   = (const float*)d_in[13];
  const float* att_w   = (const float*)d_in[14];
  const float* att_g   = (const float*)d_in[16];
  const float* att_be  = (const float*)d_in[17];

  float* ws = (float*)d_ws;
  float* lin2  = ws + OFF_LIN2;
  float* attpx = ws + OFF_ATTPX;
  float* p2raw = ws + OFF_P2;
  float* qTraw = ws + OFF_QT;
  float* attp3 = ws + OFF_ATTP3;
  short* wbf   = (short*)(ws + OFF_WBF);
  short* xT    = (short*)(ws + OFF_XT);
  float* rows4 = ws + OFF_ROWS;
  float* spart = ws + OFF_SPART;
  float* scl   = ws + OFF_SCL;

  k1_lin<<<192, 256, 0, stream>>>(inputs, theta_w, phi_w, lin2, spart);
  kconvxt<<<3584, 256, 0, stream>>>(att_w, inputs, wbf, xT);
  k2_fin<<<1, 256, 0, stream>>>(spart, theta_g, theta_be, phi_g, phi_be, scl);
  k3_gemm<<<128, 256, 0, stream>>>(lin2, scl, re_w, p2raw, qTraw, rows4);
  k4_relstats<<<1, 64, 0, stream>>>(rows4, re_g, re_be, scl);
  k5_mfma<<<512, 256, 0, stream>>>(wbf, xT, p2raw, qTraw, scl, attpx, attp3);
  k67<<<512, 256, 0, stream>>>(attpx, attp3, inputs, att_g, att_be, (float*)d_out);
}